// Round 14
// baseline (213.254 us; speedup 1.0000x reference)
//
#include <hip/hip_runtime.h>

#define NN 50000
#define NE 800000
#define NB 782        // buckets of 64 nodes
#define NBLK 256      // p12 blocks
#define CHUNK 3125    // NBLK * CHUNK == NE exactly
#define CAP 1536      // per-bucket slot cap (mean 1024)
#define CAPTOT (NB * CAP)

typedef float f32x4 __attribute__((ext_vector_type(4)));   // native vector for nontemporal store

// bf16 helpers (raw ushort storage, fp32 math)
__device__ __forceinline__ float blo(unsigned u) { return __uint_as_float(u << 16); }
__device__ __forceinline__ float bhi(unsigned u) { return __uint_as_float(u & 0xFFFF0000u); }
__device__ __forceinline__ unsigned short f2b(float f) {   // round-to-nearest-even
    unsigned u = __float_as_uint(f);
    return (unsigned short)((u + 0x7FFFu + ((u >> 16) & 1u)) >> 16);
}

// ---- single-pass bucket scatter: LDS-stage chunk, LDS hist, global reserve, scatter ----
__global__ __launch_bounds__(256) void p12(const int* __restrict__ src,
        const int* __restrict__ dst, const float* __restrict__ w,
        int* __restrict__ cursor, int2* __restrict__ stage) {
    __shared__ unsigned se[CHUNK];
    __shared__ float    sw[CHUNK];
    __shared__ int      lh[NB];
    int t = threadIdx.x;
    for (int i = t; i < NB; i += 256) lh[i] = 0;
    __syncthreads();
    int e0 = blockIdx.x * CHUNK;
    for (int i = t; i < CHUNK; i += 256) {
        int e = e0 + i;
        unsigned d = (unsigned)dst[e];
        unsigned s = (unsigned)src[e];
        float wv = w[e];
        unsigned pk = 0xFFFFFFFFu;   // invalid marker
        if (d < NN) {
            pk = (s & 0xFFFFu) | ((d & 63u) << 16) | ((d >> 6) << 22);
            atomicAdd(&lh[d >> 6], 1);
        }
        se[i] = pk;
        sw[i] = wv;
    }
    __syncthreads();
    for (int i = t; i < NB; i += 256) {
        int c = lh[i];
        lh[i] = c ? (i * CAP + atomicAdd(&cursor[i], c)) : 0;  // global write cursor
    }
    __syncthreads();
    for (int i = t; i < CHUNK; i += 256) {
        unsigned pk = se[i];
        if (pk != 0xFFFFFFFFu) {
            int bucket = (int)(pk >> 22);
            int pos = atomicAdd(&lh[bucket], 1);    // LDS atomic
            if (pos < (bucket + 1) * CAP)
                stage[pos] = make_int2((int)(pk & 0x3FFFFFu), __float_as_int(sw[i]));
        }
    }
}

// ---- per-bucket row sort + DEGREE-SORT permutation ----
// Emits (all in perm space): rowinfo(ptr,deg), dinv, p2o; inv (orig->perm); csr4 (src in ORIG ids).
__global__ __launch_bounds__(256) void p3_sort(const int2* __restrict__ stage,
        const int* __restrict__ cursor, unsigned* __restrict__ csr4,
        int2* __restrict__ rowinfo, float* __restrict__ dinv,
        int* __restrict__ p2o, int* __restrict__ inv) {
    __shared__ int   hist[64];
    __shared__ int   start[64];
    __shared__ int   cur[64];
    __shared__ int   key[64];
    __shared__ float wsum[64];
    int b = blockIdx.x, t = threadIdx.x;
    int g0 = b * CAP;
    int cnt = cursor[b];
    if (cnt > CAP) cnt = CAP;
    int g1 = g0 + cnt;
    if (t < 64) { hist[t] = 0; wsum[t] = 0.f; }
    __syncthreads();
    for (int j = g0 + t; j < g1; j += 256) {
        int2 pk = stage[j];
        int r = (pk.x >> 16) & 63;
        atomicAdd(&hist[r], 1);
        atomicAdd(&wsum[r], __int_as_float(pk.y));   // fused weighted degree (fp32)
    }
    __syncthreads();
    if (t == 0) {
        int s = g0;
        for (int r = 0; r < 64; ++r) { start[r] = s; s += hist[r]; }
    }
    __syncthreads();
    if (t < 64) {
        cur[t] = start[t];
        key[t] = (b * 64 + t < NN) ? hist[t] : 0x7FFFFFFF;   // invalid nodes sort last
    }
    __syncthreads();
    if (t < 64) {
        int n = b * 64 + t;
        if (n < NN) {
            int kt = key[t], rank = 0;
            for (int j = 0; j < 64; ++j) {
                int kj = key[j];
                rank += (kj < kt) || (kj == kt && j < t);
            }
            int p = b * 64 + rank;           // perm slot (valid nodes occupy low ranks)
            rowinfo[p] = make_int2(start[t], hist[t]);
            dinv[p] = rsqrtf(wsum[t] + 1.0f);
            p2o[p] = n;
            inv[n] = p;
        }
    }
    __syncthreads();
    for (int j = g0 + t; j < g1; j += 256) {
        int2 pk = stage[j];
        int r = (pk.x >> 16) & 63;
        int pos = atomicAdd(&cur[r], 1);
        csr4[pos] = (unsigned)(pk.x & 0xFFFF) |
                    ((unsigned)f2b(__int_as_float(pk.y)) << 16);
    }
}

// ---- remap csr src ids from original to perm space ----
__global__ __launch_bounds__(256) void remap_kernel(unsigned* __restrict__ csr4,
                                                    const int* __restrict__ inv) {
    int j = blockIdx.x * 256 + threadIdx.x;
    if (j < CAPTOT) {
        unsigned v = csr4[j];
        unsigned s = v & 0xFFFFu;
        if (s < NN) csr4[j] = (v & 0xFFFF0000u) | (unsigned)inv[s];
    }
}

// ---- layer-0 GEMM: x rows fetched via p2o (perm order); hp written perm-contiguous ----
__global__ __launch_bounds__(256) void gemm0_kernel(const float* __restrict__ x,
        const float* __restrict__ W, const float* __restrict__ dinv,
        const int* __restrict__ p2o, unsigned short* __restrict__ hp) {
    __shared__ float xs[16][64];
    int t = threadIdx.x;
    int base = blockIdx.x * 16;
    int grp = t >> 6, l = t & 63;
    for (int rr = grp; rr < 16; rr += 4) {
        int orig = p2o[base + rr];
        xs[rr][l] = x[(size_t)orig * 64 + l];    // coalesced 256B row read
    }
    __syncthreads();
    float wc[64];
#pragma unroll
    for (int k = 0; k < 64; ++k) wc[k] = W[k * 64 + l];
    float a0 = 0.f, a1 = 0.f, a2 = 0.f, a3 = 0.f;
#pragma unroll
    for (int k = 0; k < 64; ++k) {
        float wk = wc[k];
        a0 += xs[grp     ][k] * wk;
        a1 += xs[grp +  4][k] * wk;
        a2 += xs[grp +  8][k] * wk;
        a3 += xs[grp + 12][k] * wk;
    }
    int r = base + grp;
    hp[(size_t)(r     ) * 64 + l] = f2b(dinv[r     ] * a0);
    hp[(size_t)(r +  4) * 64 + l] = f2b(dinv[r +  4] * a1);
    hp[(size_t)(r +  8) * 64 + l] = f2b(dinv[r +  8] * a2);
    hp[(size_t)(r + 12) * 64 + l] = f2b(dinv[r + 12] * a3);
}

// gather body (quarter-wave per perm-node): 16 lanes x uint2 = one 128B bf16 row.
__device__ __forceinline__ float4 gather_row(int p, int fq, int qbase,
        const int2* __restrict__ rowinfo, const unsigned* __restrict__ csr4,
        const uint2* __restrict__ hp64) {
    int2 ri = rowinfo[p];
    int s0 = ri.x;
    int s1 = ri.x + ri.y;
    uint2 self = hp64[(size_t)p * 16 + fq];
    float ax = blo(self.x), ay = bhi(self.x), az = blo(self.y), aw = bhi(self.y);
    float bx = 0.f, by = 0.f, bz = 0.f, bw = 0.f;
    for (int base = s0; base < s1; base += 16) {
        int j = base + fq;
        unsigned meta = 0u;      // src=0, w=+0.0 -> contributes nothing
        if (j < s1) meta = __builtin_nontemporal_load(&csr4[j]);
        int m = s1 - base; if (m > 16) m = 16;
        int jj = 0;
        for (; jj + 4 <= m; jj += 4) {
            unsigned m0 = __shfl(meta, qbase + jj + 0);
            unsigned m1 = __shfl(meta, qbase + jj + 1);
            unsigned m2 = __shfl(meta, qbase + jj + 2);
            unsigned m3 = __shfl(meta, qbase + jj + 3);
            uint2 u0 = hp64[(size_t)(m0 & 0xFFFFu) * 16 + fq];
            uint2 u1 = hp64[(size_t)(m1 & 0xFFFFu) * 16 + fq];
            uint2 u2 = hp64[(size_t)(m2 & 0xFFFFu) * 16 + fq];
            uint2 u3 = hp64[(size_t)(m3 & 0xFFFFu) * 16 + fq];
            float w0 = __uint_as_float(m0 & 0xFFFF0000u);
            float w1 = __uint_as_float(m1 & 0xFFFF0000u);
            float w2 = __uint_as_float(m2 & 0xFFFF0000u);
            float w3 = __uint_as_float(m3 & 0xFFFF0000u);
            ax += w0 * blo(u0.x); ay += w0 * bhi(u0.x); az += w0 * blo(u0.y); aw += w0 * bhi(u0.y);
            bx += w1 * blo(u1.x); by += w1 * bhi(u1.x); bz += w1 * blo(u1.y); bw += w1 * bhi(u1.y);
            ax += w2 * blo(u2.x); ay += w2 * bhi(u2.x); az += w2 * blo(u2.y); aw += w2 * bhi(u2.y);
            bx += w3 * blo(u3.x); by += w3 * bhi(u3.x); bz += w3 * blo(u3.y); bw += w3 * bhi(u3.y);
        }
        for (; jj < m; ++jj) {
            unsigned mm = __shfl(meta, qbase + jj);
            uint2 u0 = hp64[(size_t)(mm & 0xFFFFu) * 16 + fq];
            float w0 = __uint_as_float(mm & 0xFFFF0000u);
            ax += w0 * blo(u0.x); ay += w0 * bhi(u0.x); az += w0 * blo(u0.y); aw += w0 * bhi(u0.y);
        }
    }
    return make_float4(ax + bx, ay + by, az + bz, aw + bw);
}

// fused: gather(hp_cur) -> y = relu(...) -> hp_next = bf16(dinv * (y @ Wn)); all perm space
__global__ __launch_bounds__(256) void fused_kernel(const int2* __restrict__ rowinfo,
        const unsigned* __restrict__ csr4, const float* __restrict__ dinv,
        const uint2* __restrict__ hp_cur, const float* __restrict__ bias,
        const float* __restrict__ Wn, unsigned short* __restrict__ hp_next) {
    __shared__ float ys[16][64];
    int t = threadIdx.x;
    int lane = t & 63, q = lane >> 4, fq = lane & 15;
    int ni = ((t >> 6) << 2) + q;
    int n = blockIdx.x * 16 + ni;
    float4 g = gather_row(n, fq, q << 4, rowinfo, csr4, hp_cur);
    float dv = dinv[n];
    float4 bb = ((const float4*)bias)[fq];
    float4 y;
    y.x = fmaxf(dv * g.x + bb.x, 0.f);
    y.y = fmaxf(dv * g.y + bb.y, 0.f);
    y.z = fmaxf(dv * g.z + bb.z, 0.f);
    y.w = fmaxf(dv * g.w + bb.w, 0.f);
    ((float4*)ys[ni])[fq] = y;
    __syncthreads();
    int col = lane, rq = t >> 6;
    float wc[64];
#pragma unroll
    for (int k = 0; k < 64; ++k) wc[k] = Wn[k * 64 + col];
    float a0 = 0.f, a1 = 0.f, a2 = 0.f, a3 = 0.f;
#pragma unroll
    for (int k = 0; k < 64; ++k) {
        float wk = wc[k];
        a0 += ys[rq     ][k] * wk;
        a1 += ys[rq +  4][k] * wk;
        a2 += ys[rq +  8][k] * wk;
        a3 += ys[rq + 12][k] * wk;
    }
    int r = blockIdx.x * 16 + rq;
    hp_next[(size_t)(r     ) * 64 + col] = f2b(dinv[r     ] * a0);
    hp_next[(size_t)(r +  4) * 64 + col] = f2b(dinv[r +  4] * a1);
    hp_next[(size_t)(r +  8) * 64 + col] = f2b(dinv[r +  8] * a2);
    hp_next[(size_t)(r + 12) * 64 + col] = f2b(dinv[r + 12] * a3);
}

// final layer: gather + bias + relu -> fp32 out at ORIGINAL node position
__global__ __launch_bounds__(256) void final_kernel(const int2* __restrict__ rowinfo,
        const unsigned* __restrict__ csr4, const float* __restrict__ dinv,
        const uint2* __restrict__ hp_cur, const float* __restrict__ bias,
        const int* __restrict__ p2o, float* __restrict__ out) {
    int t = threadIdx.x;
    int lane = t & 63, q = lane >> 4, fq = lane & 15;
    int n = blockIdx.x * 16 + ((t >> 6) << 2) + q;
    float4 g = gather_row(n, fq, q << 4, rowinfo, csr4, hp_cur);
    float dv = dinv[n];
    float4 bb = ((const float4*)bias)[fq];
    f32x4 r;
    r.x = fmaxf(dv * g.x + bb.x, 0.f);
    r.y = fmaxf(dv * g.y + bb.y, 0.f);
    r.z = fmaxf(dv * g.z + bb.z, 0.f);
    r.w = fmaxf(dv * g.w + bb.w, 0.f);
    int orig = p2o[n];
    __builtin_nontemporal_store(r, &((f32x4*)out)[(size_t)orig * 16 + fq]);
}

extern "C" void kernel_launch(void* const* d_in, const int* in_sizes, int n_in,
                              void* d_out, int out_size, void* d_ws, size_t ws_size,
                              hipStream_t stream) {
    const float* x  = (const float*)d_in[0];
    const int*   ei = (const int*)d_in[1];    // int32 [2, NE] flat
    const float* ew = (const float*)d_in[2];
    const float* W0 = (const float*)d_in[3];
    const float* b0 = (const float*)d_in[4];
    const float* W1 = (const float*)d_in[5];
    const float* b1 = (const float*)d_in[6];
    const float* W2 = (const float*)d_in[7];
    const float* b2 = (const float*)d_in[8];
    float*       out = (float*)d_out;

    const int* src = ei;
    const int* dst = ei + NE;

    // workspace layout (int2 arrays first for 8B alignment), ~29 MB total
    int2*     stage   = (int2*)d_ws;                     // CAPTOT (9.6 MB)
    int2*     rowinfo = stage + CAPTOT;                  // NN (perm space)
    unsigned* csr4    = (unsigned*)(rowinfo + NN);       // CAPTOT (4.8 MB)
    int*      cursor  = (int*)(csr4 + CAPTOT);           // NB
    float*    dinv    = (float*)(cursor + NB);           // NN (perm space)
    int*      p2o     = (int*)(dinv + NN);               // NN perm->orig
    int*      inv     = p2o + NN;                        // NN orig->perm
    unsigned short* hpA = (unsigned short*)(inv + NN);   // NN*64 bf16 (6.4 MB, perm space)
    unsigned short* hpB = hpA + (size_t)NN * 64;         // NN*64 bf16 (6.4 MB, perm space)

    // ---- CSR build + degree-sorted permutation (once, shared by all 3 layers) ----
    (void)hipMemsetAsync(cursor, 0, NB * sizeof(int), stream);
    p12<<<NBLK, 256, 0, stream>>>(src, dst, ew, cursor, stage);
    p3_sort<<<NB, 256, 0, stream>>>(stage, cursor, csr4, rowinfo, dinv, p2o, inv);
    remap_kernel<<<(CAPTOT + 255) / 256, 256, 0, stream>>>(csr4, inv);

    // ---- layer pipeline: gemm0 -> fused(l0->l1) -> fused(l1->l2) -> final ----
    gemm0_kernel<<<NN / 16, 256, 0, stream>>>(x, W0, dinv, p2o, hpA);
    fused_kernel<<<NN / 16, 256, 0, stream>>>(rowinfo, csr4, dinv,
            (const uint2*)hpA, b0, W1, hpB);
    fused_kernel<<<NN / 16, 256, 0, stream>>>(rowinfo, csr4, dinv,
            (const uint2*)hpB, b1, W2, hpA);
    final_kernel<<<NN / 16, 256, 0, stream>>>(rowinfo, csr4, dinv,
            (const uint2*)hpA, b2, p2o, out);
}

// Round 15
// 203.187 us; speedup vs baseline: 1.0495x; 1.0495x over previous
//
#include <hip/hip_runtime.h>

#define NN 50000
#define NE 800000
#define NB 782        // buckets of 64 nodes
#define NBLK 256      // p12 blocks
#define CHUNK 3125    // NBLK * CHUNK == NE exactly
#define CAP 1536      // per-bucket slot cap (mean 1024)
#define CAPTOT (NB * CAP)

typedef float f32x4 __attribute__((ext_vector_type(4)));   // native vector for nontemporal store

// bf16 helpers (raw ushort storage, fp32 math)
__device__ __forceinline__ float blo(unsigned u) { return __uint_as_float(u << 16); }
__device__ __forceinline__ float bhi(unsigned u) { return __uint_as_float(u & 0xFFFF0000u); }
__device__ __forceinline__ unsigned short f2b(float f) {   // round-to-nearest-even
    unsigned u = __float_as_uint(f);
    return (unsigned short)((u + 0x7FFFu + ((u >> 16) & 1u)) >> 16);
}

// ---- single-pass bucket scatter: LDS-stage chunk, LDS hist, global reserve, scatter ----
// cursor[] is zero-initialized (hipMemsetAsync); slots are bucket-relative.
__global__ __launch_bounds__(256) void p12(const int* __restrict__ src,
        const int* __restrict__ dst, const float* __restrict__ w,
        int* __restrict__ cursor, int2* __restrict__ stage) {
    __shared__ unsigned se[CHUNK];
    __shared__ float    sw[CHUNK];
    __shared__ int      lh[NB];
    int t = threadIdx.x;
    for (int i = t; i < NB; i += 256) lh[i] = 0;
    __syncthreads();
    int e0 = blockIdx.x * CHUNK;
    for (int i = t; i < CHUNK; i += 256) {
        int e = e0 + i;
        unsigned d = (unsigned)dst[e];
        unsigned s = (unsigned)src[e];
        float wv = w[e];
        unsigned pk = 0xFFFFFFFFu;   // invalid marker
        if (d < NN) {
            pk = (s & 0xFFFFu) | ((d & 63u) << 16) | ((d >> 6) << 22);
            atomicAdd(&lh[d >> 6], 1);
        }
        se[i] = pk;
        sw[i] = wv;
    }
    __syncthreads();
    for (int i = t; i < NB; i += 256) {
        int c = lh[i];
        lh[i] = c ? (i * CAP + atomicAdd(&cursor[i], c)) : 0;  // global write cursor
    }
    __syncthreads();
    for (int i = t; i < CHUNK; i += 256) {
        unsigned pk = se[i];
        if (pk != 0xFFFFFFFFu) {
            int bucket = (int)(pk >> 22);
            int pos = atomicAdd(&lh[bucket], 1);    // LDS atomic
            if (pos < (bucket + 1) * CAP)
                stage[pos] = make_int2((int)(pk & 0x3FFFFFu), __float_as_int(sw[i]));
        }
    }
}

// ---- per-bucket row sort: stage -> 4B csr (src16 | w-bf16); emit row_ptr/row_deg/dinv ----
__global__ __launch_bounds__(256) void p3_sort(const int2* __restrict__ stage,
        const int* __restrict__ cursor, unsigned* __restrict__ csr4,
        int* __restrict__ row_ptr, int* __restrict__ row_deg, float* __restrict__ dinv) {
    __shared__ int   hist[64];
    __shared__ int   cur[64];
    __shared__ float wsum[64];
    int b = blockIdx.x, t = threadIdx.x;
    int g0 = b * CAP;
    int cnt = cursor[b];
    if (cnt > CAP) cnt = CAP;
    int g1 = g0 + cnt;
    if (t < 64) { hist[t] = 0; wsum[t] = 0.f; }
    __syncthreads();
    for (int j = g0 + t; j < g1; j += 256) {
        int2 pk = stage[j];
        int r = (pk.x >> 16) & 63;
        atomicAdd(&hist[r], 1);
        atomicAdd(&wsum[r], __int_as_float(pk.y));   // fused weighted degree (fp32)
    }
    __syncthreads();
    if (t == 0) {
        int s = g0;
        for (int r = 0; r < 64; ++r) { cur[r] = s; s += hist[r]; }
    }
    __syncthreads();
    if (t < 64) {
        int n = b * 64 + t;
        if (n < NN) {
            row_ptr[n] = cur[t];
            row_deg[n] = hist[t];
            dinv[n] = rsqrtf(wsum[t] + 1.0f);
        }
    }
    __syncthreads();
    for (int j = g0 + t; j < g1; j += 256) {
        int2 pk = stage[j];
        int r = (pk.x >> 16) & 63;
        int pos = atomicAdd(&cur[r], 1);
        csr4[pos] = (unsigned)(pk.x & 0xFFFF) |
                    ((unsigned)f2b(__int_as_float(pk.y)) << 16);
    }
}

// hp[N,64] = bf16( dinv[r] * (x[N,64] @ W[64,64]) ); 16 rows/block
__global__ __launch_bounds__(256) void gemm_pre_kernel(const float* __restrict__ x,
        const float* __restrict__ W, const float* __restrict__ dinv,
        unsigned short* __restrict__ hp) {
    __shared__ float xs[16][64];
    int t = threadIdx.x;
    int base = blockIdx.x * 16;
    for (int idx = t; idx < 16 * 64; idx += 256)
        xs[idx >> 6][idx & 63] = x[(size_t)(base + (idx >> 6)) * 64 + (idx & 63)];
    __syncthreads();
    int col = t & 63, rq = t >> 6;
    float wc[64];
#pragma unroll
    for (int k = 0; k < 64; ++k) wc[k] = W[k * 64 + col];
    float a0 = 0.f, a1 = 0.f, a2 = 0.f, a3 = 0.f;
#pragma unroll
    for (int k = 0; k < 64; ++k) {
        float wk = wc[k];
        a0 += xs[rq     ][k] * wk;
        a1 += xs[rq +  4][k] * wk;
        a2 += xs[rq +  8][k] * wk;
        a3 += xs[rq + 12][k] * wk;
    }
    int r = base + rq;
    hp[(size_t)(r     ) * 64 + col] = f2b(dinv[r     ] * a0);
    hp[(size_t)(r +  4) * 64 + col] = f2b(dinv[r +  4] * a1);
    hp[(size_t)(r +  8) * 64 + col] = f2b(dinv[r +  8] * a2);
    hp[(size_t)(r + 12) * 64 + col] = f2b(dinv[r + 12] * a3);
}

// gather body (quarter-wave per node): 16 lanes x uint2 = one 128B bf16 row.
// csr read via nontemporal load (streaming, zero reuse) to preserve hp L2 residency.
__device__ __forceinline__ float4 gather_row(int n, int fq, int qbase,
        const int* __restrict__ row_ptr, const int* __restrict__ row_deg,
        const unsigned* __restrict__ csr4, const uint2* __restrict__ hp64) {
    int s0 = row_ptr[n];
    int s1 = s0 + row_deg[n];
    uint2 self = hp64[(size_t)n * 16 + fq];
    float ax = blo(self.x), ay = bhi(self.x), az = blo(self.y), aw = bhi(self.y);
    float bx = 0.f, by = 0.f, bz = 0.f, bw = 0.f;
    for (int base = s0; base < s1; base += 16) {
        int j = base + fq;
        unsigned meta = 0u;      // src=0, w=+0.0 -> contributes nothing
        if (j < s1) meta = __builtin_nontemporal_load(&csr4[j]);
        int m = s1 - base; if (m > 16) m = 16;
        int jj = 0;
        for (; jj + 4 <= m; jj += 4) {
            unsigned m0 = __shfl(meta, qbase + jj + 0);
            unsigned m1 = __shfl(meta, qbase + jj + 1);
            unsigned m2 = __shfl(meta, qbase + jj + 2);
            unsigned m3 = __shfl(meta, qbase + jj + 3);
            uint2 u0 = hp64[(size_t)(m0 & 0xFFFFu) * 16 + fq];
            uint2 u1 = hp64[(size_t)(m1 & 0xFFFFu) * 16 + fq];
            uint2 u2 = hp64[(size_t)(m2 & 0xFFFFu) * 16 + fq];
            uint2 u3 = hp64[(size_t)(m3 & 0xFFFFu) * 16 + fq];
            float w0 = __uint_as_float(m0 & 0xFFFF0000u);
            float w1 = __uint_as_float(m1 & 0xFFFF0000u);
            float w2 = __uint_as_float(m2 & 0xFFFF0000u);
            float w3 = __uint_as_float(m3 & 0xFFFF0000u);
            ax += w0 * blo(u0.x); ay += w0 * bhi(u0.x); az += w0 * blo(u0.y); aw += w0 * bhi(u0.y);
            bx += w1 * blo(u1.x); by += w1 * bhi(u1.x); bz += w1 * blo(u1.y); bw += w1 * bhi(u1.y);
            ax += w2 * blo(u2.x); ay += w2 * bhi(u2.x); az += w2 * blo(u2.y); aw += w2 * bhi(u2.y);
            bx += w3 * blo(u3.x); by += w3 * bhi(u3.x); bz += w3 * blo(u3.y); bw += w3 * bhi(u3.y);
        }
        for (; jj < m; ++jj) {
            unsigned mm = __shfl(meta, qbase + jj);
            uint2 u0 = hp64[(size_t)(mm & 0xFFFFu) * 16 + fq];
            float w0 = __uint_as_float(mm & 0xFFFF0000u);
            ax += w0 * blo(u0.x); ay += w0 * bhi(u0.x); az += w0 * blo(u0.y); aw += w0 * bhi(u0.y);
        }
    }
    return make_float4(ax + bx, ay + by, az + bz, aw + bw);
}

// fused: gather(hp_cur, bias_l) -> y = relu(...) -> hp_next = bf16(dinv * (y @ Wn))
// hp_next via PLAIN stores (next kernel gathers it — keep it cached).
__global__ __launch_bounds__(256) void fused_kernel(const int* __restrict__ row_ptr,
        const int* __restrict__ row_deg, const unsigned* __restrict__ csr4,
        const float* __restrict__ dinv, const uint2* __restrict__ hp_cur,
        const float* __restrict__ bias, const float* __restrict__ Wn,
        unsigned short* __restrict__ hp_next) {
    __shared__ float ys[16][64];
    int t = threadIdx.x;
    int lane = t & 63, q = lane >> 4, fq = lane & 15;
    int ni = ((t >> 6) << 2) + q;
    int n = blockIdx.x * 16 + ni;
    float4 g = gather_row(n, fq, q << 4, row_ptr, row_deg, csr4, hp_cur);
    float dv = dinv[n];
    float4 bb = ((const float4*)bias)[fq];
    float4 y;
    y.x = fmaxf(dv * g.x + bb.x, 0.f);
    y.y = fmaxf(dv * g.y + bb.y, 0.f);
    y.z = fmaxf(dv * g.z + bb.z, 0.f);
    y.w = fmaxf(dv * g.w + bb.w, 0.f);
    ((float4*)ys[ni])[fq] = y;
    __syncthreads();
    int col = lane, rq = t >> 6;
    float wc[64];
#pragma unroll
    for (int k = 0; k < 64; ++k) wc[k] = Wn[k * 64 + col];
    float a0 = 0.f, a1 = 0.f, a2 = 0.f, a3 = 0.f;
#pragma unroll
    for (int k = 0; k < 64; ++k) {
        float wk = wc[k];
        a0 += ys[rq     ][k] * wk;
        a1 += ys[rq +  4][k] * wk;
        a2 += ys[rq +  8][k] * wk;
        a3 += ys[rq + 12][k] * wk;
    }
    int r = blockIdx.x * 16 + rq;
    hp_next[(size_t)(r     ) * 64 + col] = f2b(dinv[r     ] * a0);
    hp_next[(size_t)(r +  4) * 64 + col] = f2b(dinv[r +  4] * a1);
    hp_next[(size_t)(r +  8) * 64 + col] = f2b(dinv[r +  8] * a2);
    hp_next[(size_t)(r + 12) * 64 + col] = f2b(dinv[r + 12] * a3);
}

// final layer: gather + bias + relu -> fp32 out (write-once: nontemporal)
__global__ __launch_bounds__(256) void final_kernel(const int* __restrict__ row_ptr,
        const int* __restrict__ row_deg, const unsigned* __restrict__ csr4,
        const float* __restrict__ dinv, const uint2* __restrict__ hp_cur,
        const float* __restrict__ bias, float* __restrict__ out) {
    int t = threadIdx.x;
    int lane = t & 63, q = lane >> 4, fq = lane & 15;
    int n = blockIdx.x * 16 + ((t >> 6) << 2) + q;
    float4 g = gather_row(n, fq, q << 4, row_ptr, row_deg, csr4, hp_cur);
    float dv = dinv[n];
    float4 bb = ((const float4*)bias)[fq];
    f32x4 r;
    r.x = fmaxf(dv * g.x + bb.x, 0.f);
    r.y = fmaxf(dv * g.y + bb.y, 0.f);
    r.z = fmaxf(dv * g.z + bb.z, 0.f);
    r.w = fmaxf(dv * g.w + bb.w, 0.f);
    __builtin_nontemporal_store(r, &((f32x4*)out)[(size_t)n * 16 + fq]);
}

extern "C" void kernel_launch(void* const* d_in, const int* in_sizes, int n_in,
                              void* d_out, int out_size, void* d_ws, size_t ws_size,
                              hipStream_t stream) {
    const float* x  = (const float*)d_in[0];
    const int*   ei = (const int*)d_in[1];    // int32 [2, NE] flat
    const float* ew = (const float*)d_in[2];
    const float* W0 = (const float*)d_in[3];
    const float* b0 = (const float*)d_in[4];
    const float* W1 = (const float*)d_in[5];
    const float* b1 = (const float*)d_in[6];
    const float* W2 = (const float*)d_in[7];
    const float* b2 = (const float*)d_in[8];
    float*       out = (float*)d_out;

    const int* src = ei;
    const int* dst = ei + NE;

    // workspace layout (8B-aligned arrays first), ~28 MB total
    int2*     stage   = (int2*)d_ws;                     // CAPTOT (9.6 MB)
    unsigned* csr4    = (unsigned*)(stage + CAPTOT);     // CAPTOT (4.8 MB)
    int*      cursor  = (int*)(csr4 + CAPTOT);           // NB
    int*      row_ptr = cursor + NB;                     // NN
    int*      row_deg = row_ptr + NN;                    // NN
    float*    dinv    = (float*)(row_deg + NN);          // NN
    unsigned short* hpA = (unsigned short*)(dinv + NN);  // NN*64 bf16 (6.4 MB)
    unsigned short* hpB = hpA + (size_t)NN * 64;         // NN*64 bf16 (6.4 MB)

    // ---- CSR build (once, shared by all 3 layers) ----
    (void)hipMemsetAsync(cursor, 0, NB * sizeof(int), stream);
    p12<<<NBLK, 256, 0, stream>>>(src, dst, ew, cursor, stage);
    p3_sort<<<NB, 256, 0, stream>>>(stage, cursor, csr4, row_ptr, row_deg, dinv);

    // ---- layer pipeline: gemm0 -> fused(l0->l1) -> fused(l1->l2) -> final ----
    gemm_pre_kernel<<<NN / 16, 256, 0, stream>>>(x, W0, dinv, hpA);
    fused_kernel<<<NN / 16, 256, 0, stream>>>(row_ptr, row_deg, csr4, dinv,
            (const uint2*)hpA, b0, W1, hpB);
    fused_kernel<<<NN / 16, 256, 0, stream>>>(row_ptr, row_deg, csr4, dinv,
            (const uint2*)hpB, b1, W2, hpA);
    final_kernel<<<NN / 16, 256, 0, stream>>>(row_ptr, row_deg, csr4, dinv,
            (const uint2*)hpA, b2, out);
}